// Round 6
// baseline (295.417 us; speedup 1.0000x reference)
//
#include <hip/hip_runtime.h>

// Reference: H = W = 2048, C = 8, N = 1e6
#define HH 2048
#define WW 2048
#define CC 8
#define MODV 2044.0f       // H - 4

#define NROWS 2044
#define NQ 4               // column quarters
#define QCOLS 512          // cols per quarter-unit
#define NB (NROWS * NQ)    // 8176 buckets: (row i0, quarter q)
#define CAP 140            // mean 122, +1.6 sigma; overflow kernel catches rest
#define OVCAP 16384

#define PSTRIDE 12         // floats per pixel in LDS (48 B) -> bank-optimal random b128 reads
#define UFLOATS (QCOLS * PSTRIDE)   // 6144 floats = 24 KB per unit

#define K1_PPT 8
#define K1_BLOCK 256
#define K1_PPB (K1_PPT * K1_BLOCK)  // 2048

#define STRIP_ROWS 16
#define NSTRIPS ((NROWS + STRIP_ROWS - 1) / STRIP_ROWS)  // 128
#define K2_BLOCKS (NQ * NSTRIPS)                          // 512 -> 2 blocks/CU (72 KB LDS)

typedef float v4f __attribute__((ext_vector_type(4)));

__device__ __forceinline__ float wrap1(float v) {
    // (v - 1) mod 2044 + 1, floored mod; idempotent on already-wrapped values
    float c = fmodf(v - 1.0f, MODV);
    if (c < 0.0f) c += MODV;
    return c + 1.0f;
}

__device__ __forceinline__ float lerp3(float tl, float tr, float bl, float br,
                                       float d0, float d1) {
    float mb = br + d0 * (bl - br);
    float mt = tr + d0 * (tl - tr);
    return mb + d1 * (mt - mb);
}

// Direct TCP-path per-point processing (fallback + overflow)
__device__ __forceinline__ void process_point_direct(
    float x, float y, int idx,
    const float* __restrict__ visible, float* __restrict__ out)
{
    float cx = wrap1(x), cy = wrap1(y);
    float fx = floorf(cx), fy = floorf(cy);
    float d0 = cx - fx, d1 = cy - fy;
    int i0 = (int)fx, i1 = (int)fy;
    const float* p00 = visible + ((size_t)i0 * WW + (size_t)i1) * CC;
    const float* p10 = p00 + (size_t)WW * CC;
    v4f tl0 = *(const v4f*)(p00);     v4f tl1 = *(const v4f*)(p00 + 4);
    v4f bl0 = *(const v4f*)(p00 + 8); v4f bl1 = *(const v4f*)(p00 + 12);
    v4f tr0 = *(const v4f*)(p10);     v4f tr1 = *(const v4f*)(p10 + 4);
    v4f br0 = *(const v4f*)(p10 + 8); v4f br1 = *(const v4f*)(p10 + 12);
    float m = (cx > (float)HH) ? 0.0f : 1.0f;
    v4f o0, o1;
    o0.x = m * lerp3(tl0.x, tr0.x, bl0.x, br0.x, d0, d1);
    o0.y = m * lerp3(tl0.y, tr0.y, bl0.y, br0.y, d0, d1);
    o0.z = m * lerp3(tl0.z, tr0.z, bl0.z, br0.z, d0, d1);
    o0.w = m * lerp3(tl0.w, tr0.w, bl0.w, br0.w, d0, d1);
    o1.x = m * lerp3(tl1.x, tr1.x, bl1.x, br1.x, d0, d1);
    o1.y = m * lerp3(tl1.y, tr1.y, bl1.y, br1.y, d0, d1);
    o1.z = m * lerp3(tl1.z, tr1.z, bl1.z, br1.z, d0, d1);
    o1.w = m * lerp3(tl1.w, tr1.w, bl1.w, br1.w, d0, d1);
    float* po = out + (size_t)idx * CC;
    *(v4f*)(po) = o0; *(v4f*)(po + 4) = o1;
}

// ---------- Kernel 1: bucketize by (row, quarter); global atomics, no LDS ----------
__global__ __launch_bounds__(K1_BLOCK) void k1_bucket(
    const float* __restrict__ coords, int n,
    unsigned int* __restrict__ cursors,   // NB counters, stride 4 dwords (16 B)
    unsigned int* __restrict__ ovcur,
    v4f* __restrict__ records,            // NB * CAP
    v4f* __restrict__ ovrec)              // OVCAP
{
    int tid = threadIdx.x;
    int blockStart = blockIdx.x * K1_PPB;
    float cxv[K1_PPT], cyv[K1_PPT];
    int bv[K1_PPT];
    unsigned int gv[K1_PPT];

#pragma unroll
    for (int i = 0; i < K1_PPT; ++i) {
        int p = blockStart + i * K1_BLOCK + tid;
        bv[i] = -1;
        if (p < n) {
            float2 co = ((const float2*)coords)[p];
            float cx = wrap1(co.x), cy = wrap1(co.y);
            cxv[i] = cx; cyv[i] = cy;
            int i0 = (int)floorf(cx);     // [1,2044]
            int i1 = (int)floorf(cy);     // [1,2044]
            if ((i1 & (QCOLS - 1)) == QCOLS - 1) {
                bv[i] = -2;               // straddles a quarter boundary
                gv[i] = atomicAdd(ovcur, 1u);
            } else {
                int q = i1 >> 9;
                int b = q * NROWS + (i0 - 1);
                bv[i] = b;
                gv[i] = atomicAdd(&cursors[(unsigned)b * 4], 1u);
            }
        }
    }
#pragma unroll
    for (int i = 0; i < K1_PPT; ++i) {
        if (bv[i] == -1) continue;
        int p = blockStart + i * K1_BLOCK + tid;
        v4f rec; rec.x = cxv[i]; rec.y = cyv[i];
        rec.z = __int_as_float(p); rec.w = 0.0f;
        if (bv[i] == -2) {
            if (gv[i] < OVCAP) ovrec[gv[i]] = rec;
        } else {
            unsigned int g = gv[i];
            if (g < CAP) records[(size_t)bv[i] * CAP + g] = rec;
            else { unsigned int o = atomicAdd(ovcur, 1u); if (o < OVCAP) ovrec[o] = rec; }
        }
    }
}

// ---------- Kernel 2: LDS-staged gather, VGPR-round-trip staging ----------
// Block = (quarter q, 16-row strip). Ring of 3 x 24 KB units (48 B/pixel pad).
// Loads for row r+2 are issued AFTER the barrier and consumed by ds_write
// BEFORE the next barrier -> no global load is in flight across any barrier,
// so the compiler's vmcnt(0)-before-s_barrier drain is cheap.
__global__ __launch_bounds__(256) void k2_process(
    const unsigned int* __restrict__ cursors,
    const v4f* __restrict__ records,
    const float* __restrict__ visible,
    float* __restrict__ out)
{
    __shared__ float ring[3][UFLOATS];   // 72 KB -> 2 blocks/CU

    int bid = blockIdx.x;
    int q = bid & 3;
    int s = bid >> 2;
    int r0 = STRIP_ROWS * s + 1;
    if (r0 > NROWS) return;
    int rend = min(r0 + STRIP_ROWS - 1, NROWS);
    int K = rend - r0 + 1;
    int tid = threadIdx.x;
    int C0 = q * QCOLS;

    v4f regs[4];   // staging buffer: 16 KB unit / 256 threads = 64 B/thread

    auto issue_load = [&](int R) {
        const v4f* g = (const v4f*)(visible + ((size_t)R * WW + C0) * CC);
#pragma unroll
        for (int i = 0; i < 4; ++i) regs[i] = g[i * 256 + tid];   // coalesced dwordx4
    };
    auto write_unit = [&](int slot) {
#pragma unroll
        for (int i = 0; i < 4; ++i) {
            int ch = i * 256 + tid;    // 16 B chunk index; pixel = ch>>1, half = ch&1
            float* dst = &ring[slot][(ch >> 1) * PSTRIDE + (ch & 1) * 4];
            *(v4f*)dst = regs[i];      // ds_write_b128, bank-spread by stride 12
        }
    };

    // Prologue: unit r0 -> slot 0; issue loads for r0+1
    issue_load(r0);
    write_unit(0);
    issue_load(r0 + 1);

    for (int k = 0; k < K; ++k) {
        write_unit((k + 1) % 3);          // row r0+k+1 (waits its loads via vmcnt)
        __syncthreads();                  // lgkm drain only; no loads in flight
        if (k + 2 <= K) issue_load(r0 + k + 2);   // overlaps with gather below

        int r = r0 + k;
        int b = q * NROWS + (r - 1);
        unsigned int cnt = cursors[(unsigned)b * 4];
        if (cnt > CAP) cnt = CAP;

        const float* uA = ring[k % 3];        // row r   (= i0)
        const float* uB = ring[(k + 1) % 3];  // row r+1

        for (unsigned int slot = tid; slot < cnt; slot += 256) {
            v4f rec = records[(size_t)b * CAP + slot];   // coalesced 16 B
            float cx = rec.x, cy = rec.y;                // pre-wrapped
            float fy = floorf(cy);
            float d0 = cx - (float)r;                    // floor(cx) == r by bucketing
            float d1 = cy - fy;
            int c = (int)fy - C0;                        // [0,510]; c+1 <= 511

            const float* pA = uA + c * PSTRIDE;
            const float* pB = uB + c * PSTRIDE;
            v4f tl0 = *(const v4f*)(pA);
            v4f tl1 = *(const v4f*)(pA + 4);
            v4f bl0 = *(const v4f*)(pA + PSTRIDE);
            v4f bl1 = *(const v4f*)(pA + PSTRIDE + 4);
            v4f tr0 = *(const v4f*)(pB);
            v4f tr1 = *(const v4f*)(pB + 4);
            v4f br0 = *(const v4f*)(pB + PSTRIDE);
            v4f br1 = *(const v4f*)(pB + PSTRIDE + 4);

            float m = (cx > (float)HH) ? 0.0f : 1.0f;    // reference fidelity
            v4f o0, o1;
            o0.x = m * lerp3(tl0.x, tr0.x, bl0.x, br0.x, d0, d1);
            o0.y = m * lerp3(tl0.y, tr0.y, bl0.y, br0.y, d0, d1);
            o0.z = m * lerp3(tl0.z, tr0.z, bl0.z, br0.z, d0, d1);
            o0.w = m * lerp3(tl0.w, tr0.w, bl0.w, br0.w, d0, d1);
            o1.x = m * lerp3(tl1.x, tr1.x, bl1.x, br1.x, d0, d1);
            o1.y = m * lerp3(tl1.y, tr1.y, bl1.y, br1.y, d0, d1);
            o1.z = m * lerp3(tl1.z, tr1.z, bl1.z, br1.z, d0, d1);
            o1.w = m * lerp3(tl1.w, tr1.w, bl1.w, br1.w, d0, d1);

            float* po = out + (size_t)__float_as_int(rec.z) * CC;
            *(v4f*)(po) = o0; *(v4f*)(po + 4) = o1;
        }
    }
}

// ---------- Kernel 2b: overflow + quarter-boundary straddlers ----------
__global__ __launch_bounds__(256) void k2_overflow(
    const unsigned int* __restrict__ ovcur,
    const v4f* __restrict__ ovrec,
    const float* __restrict__ visible,
    float* __restrict__ out)
{
    unsigned int cnt = *ovcur;
    if (cnt > OVCAP) cnt = OVCAP;
    unsigned int s = blockIdx.x * 256 + threadIdx.x;
    if (s >= cnt) return;
    v4f rec = ovrec[s];
    process_point_direct(rec.x, rec.y, __float_as_int(rec.z), visible, out);
}

// ---------- Fallback: direct gather (R1 structure) ----------
__global__ __launch_bounds__(256) void idx2pixel_direct(
    const float* __restrict__ coords,
    const float* __restrict__ visible,
    float* __restrict__ out, int n)
{
    int t = blockIdx.x * blockDim.x + threadIdx.x;
    if (t >= n) return;
    float2 co = *reinterpret_cast<const float2*>(coords + 2 * (size_t)t);
    process_point_direct(co.x, co.y, t, visible, out);
}

extern "C" void kernel_launch(void* const* d_in, const int* in_sizes, int n_in,
                              void* d_out, int out_size, void* d_ws, size_t ws_size,
                              hipStream_t stream) {
    const float* coords  = (const float*)d_in[0];  // (N, 2) fp32
    const float* visible = (const float*)d_in[1];  // (2048, 2048, 8) fp32
    float* out = (float*)d_out;                    // (N, 8) fp32
    int n = in_sizes[0] / 2;

    // ws layout: [0, NB*16) cursors (16 B stride) | ovcur @ NB*16 |
    //            records @ 131072 | ovrec after records
    const size_t CUR_BYTES = (size_t)NB * 16;                 // 130,816
    const size_t REC_OFF   = 131072;
    const size_t REC_BYTES = (size_t)NB * CAP * 16;           // 18,314,240
    const size_t NEED = REC_OFF + REC_BYTES + (size_t)OVCAP * 16;   // ~17.8 MiB

    if (ws_size >= NEED && n <= 1100000) {
        unsigned int* cursors = (unsigned int*)d_ws;
        unsigned int* ovcur   = (unsigned int*)((char*)d_ws + CUR_BYTES);
        v4f* records          = (v4f*)((char*)d_ws + REC_OFF);
        v4f* ovrec            = (v4f*)((char*)d_ws + REC_OFF + REC_BYTES);

        hipMemsetAsync(d_ws, 0, REC_OFF, stream);   // zero cursors + ovcur

        int k1_blocks = (n + K1_PPB - 1) / K1_PPB;
        k1_bucket<<<k1_blocks, K1_BLOCK, 0, stream>>>(coords, n, cursors, ovcur,
                                                      records, ovrec);
        k2_process<<<K2_BLOCKS, 256, 0, stream>>>(cursors, records, visible, out);
        k2_overflow<<<OVCAP / 256, 256, 0, stream>>>(ovcur, ovrec, visible, out);
    } else {
        int block = 256;
        int grid = (n + block - 1) / block;
        idx2pixel_direct<<<grid, block, 0, stream>>>(coords, visible, out, n);
    }
}